// Round 1
// baseline (37.967 us; speedup 1.0000x reference)
//
#include <hip/hip_runtime.h>

// MoE router: x [16384, 2048] f32, gate_w [8, 2048] f32
// outputs (concatenated f32): weights [16384,2] | mask [8,2,16384] | logits [16384,8]

constexpr int kN = 16384;
constexpr int kD = 2048;
constexpr int kE = 8;

__global__ __launch_bounds__(256, 4)
void moe_router_kernel(const float* __restrict__ x,
                       const float* __restrict__ gw,
                       float* __restrict__ out)
{
    const int lane = threadIdx.x & 63;
    const int wv   = threadIdx.x >> 6;
    const int n0   = blockIdx.x * 16 + wv * 4;   // 4 rows per wave

    const float* xr = x + (long)n0 * kD;

    float acc[4][8];
#pragma unroll
    for (int r = 0; r < 4; ++r)
#pragma unroll
        for (int e = 0; e < 8; ++e) acc[r][e] = 0.f;

    // Main sweep: 8 col-iterations, 64 lanes x float4 = 256 cols each.
#pragma unroll
    for (int it = 0; it < 8; ++it) {
        const int c = it * 256 + lane * 4;
        float4 g[8];
#pragma unroll
        for (int e = 0; e < 8; ++e)
            g[e] = *reinterpret_cast<const float4*>(gw + e * kD + c);
#pragma unroll
        for (int r = 0; r < 4; ++r) {
            const float4 xv = *reinterpret_cast<const float4*>(xr + r * kD + c);
#pragma unroll
            for (int e = 0; e < 8; ++e) {
                acc[r][e] = fmaf(xv.x, g[e].x, acc[r][e]);
                acc[r][e] = fmaf(xv.y, g[e].y, acc[r][e]);
                acc[r][e] = fmaf(xv.z, g[e].z, acc[r][e]);
                acc[r][e] = fmaf(xv.w, g[e].w, acc[r][e]);
            }
        }
    }

    // Full-wave butterfly: every lane ends with all 32 (row, expert) logits.
#pragma unroll
    for (int r = 0; r < 4; ++r)
#pragma unroll
        for (int e = 0; e < 8; ++e) {
            float v = acc[r][e];
            v += __shfl_xor(v, 1);
            v += __shfl_xor(v, 2);
            v += __shfl_xor(v, 4);
            v += __shfl_xor(v, 8);
            v += __shfl_xor(v, 16);
            v += __shfl_xor(v, 32);
            acc[r][e] = v;
        }

    float* out_w = out;                            // [N, 2]
    float* out_m = out + 2 * kN;                   // [E, 2, N]
    float* out_l = out + 2 * kN + 2 * kE * kN;     // [N, 8]

    // Select row r's logits into a statically-indexed array (no scratch).
    auto load_row = [&](int r, float* le) {
#pragma unroll
        for (int e = 0; e < 8; ++e) {
            float v = acc[0][e];
            v = (r == 1) ? acc[1][e] : v;
            v = (r == 2) ? acc[2][e] : v;
            v = (r == 3) ? acc[3][e] : v;
            le[e] = v;
        }
    };
    // top-2 with lowest-index tie-break (strict > keeps earliest max).
    auto top2 = [](const float* le, int& s0, int& s1) {
        float b0 = le[0]; s0 = 0;
#pragma unroll
        for (int e = 1; e < 8; ++e)
            if (le[e] > b0) { b0 = le[e]; s0 = e; }
        float b1 = -3.4e38f; s1 = (s0 == 0) ? 1 : 0;
#pragma unroll
        for (int e = 0; e < 8; ++e)
            if (e != s0 && le[e] > b1) { b1 = le[e]; s1 = e; }
    };

    // ---- expert mask: all 64 lanes, one (e, k, row) slot each ----
    {
        const int rm = lane & 3;
        const int km = (lane >> 2) & 1;
        const int em = lane >> 3;
        float le[8]; load_row(rm, le);
        int s0, s1; top2(le, s0, s1);
        const int sel = km ? s1 : s0;
        out_m[(long)em * (2 * kN) + (long)km * kN + (n0 + rm)] =
            (sel == em) ? 1.0f : 0.0f;
    }

    // ---- weights: lanes 0..7, one (row, k) each ----
    if (lane < 8) {
        const int rw = lane >> 1;
        const int kw = lane & 1;
        float le[8]; load_row(rw, le);
        int s0, s1; top2(le, s0, s1);
        float v0 = le[0], v1 = le[0];
#pragma unroll
        for (int e = 1; e < 8; ++e) {
            v0 = (e == s0) ? le[e] : v0;
            v1 = (e == s1) ? le[e] : v1;
        }
        const float d  = expf(v1 - v0);        // <= 1
        const float w0 = 1.0f / (1.0f + d);    // = p0/(p0+p1)
        out_w[(long)(n0 + rw) * 2 + kw] = kw ? (d * w0) : w0;
    }

    // ---- gate logits: lanes 0..31, one (row, e) each (coalesced 128B/row-grp) ----
    if (lane < 32) {
        const int rl = lane >> 3;
        const int el = lane & 7;
        float le[8]; load_row(rl, le);
        float v = le[0];
#pragma unroll
        for (int e = 1; e < 8; ++e)
            v = (e == el) ? le[e] : v;
        out_l[(long)(n0 + rl) * 8 + el] = v;
    }
}

extern "C" void kernel_launch(void* const* d_in, const int* in_sizes, int n_in,
                              void* d_out, int out_size, void* d_ws, size_t ws_size,
                              hipStream_t stream)
{
    (void)in_sizes; (void)n_in; (void)d_ws; (void)ws_size; (void)out_size;
    const float* x  = (const float*)d_in[0];
    const float* gw = (const float*)d_in[1];
    float* out = (float*)d_out;

    dim3 grid(kN / 16);   // 1024 blocks, 16 rows each
    dim3 block(256);
    moe_router_kernel<<<grid, block, 0, stream>>>(x, gw, out);
}

// Round 2
// 32.653 us; speedup vs baseline: 1.1627x; 1.1627x over previous
//
#include <hip/hip_runtime.h>
#include <math.h>

// MoE router: x [16384, 2048] f32, gate_w [8, 2048] f32
// outputs (concatenated f32): weights [16384,2] | mask [8,2,16384] | logits [16384,8]

constexpr int kN = 16384;
constexpr int kD = 2048;
constexpr int kE = 8;

using f4 = __attribute__((ext_vector_type(4))) float;

__global__ __launch_bounds__(256, 4)
void moe_router_kernel(const float* __restrict__ x,
                       const float* __restrict__ gw,
                       float* __restrict__ out)
{
    const int lane = threadIdx.x & 63;
    const int wv   = threadIdx.x >> 6;
    const int n0   = blockIdx.x * 16 + wv * 4;   // 4 rows per wave

    const float* xr = x + (long)n0 * kD;

    float acc[4][8];
#pragma unroll
    for (int r = 0; r < 4; ++r)
#pragma unroll
        for (int e = 0; e < 8; ++e) acc[r][e] = 0.f;

    // Main sweep: 8 col-iterations, 64 lanes x float4 = 256 cols each.
    // unroll 1: keeps live regs ~90 (< the 128 cap from launch_bounds) -> no spills.
#pragma unroll 1
    for (int it = 0; it < 8; ++it) {
        const int c = it * 256 + lane * 4;
        // x first (HBM, longest latency), nontemporal (single-use stream,
        // keep L2 for gate_w).
        f4 xv[4];
#pragma unroll
        for (int r = 0; r < 4; ++r)
            xv[r] = __builtin_nontemporal_load(
                reinterpret_cast<const f4*>(xr + (long)r * kD + c));
        f4 g[8];
#pragma unroll
        for (int e = 0; e < 8; ++e)
            g[e] = *reinterpret_cast<const f4*>(gw + e * kD + c);
#pragma unroll
        for (int r = 0; r < 4; ++r)
#pragma unroll
            for (int e = 0; e < 8; ++e) {
                acc[r][e] = fmaf(xv[r].x, g[e].x, acc[r][e]);
                acc[r][e] = fmaf(xv[r].y, g[e].y, acc[r][e]);
                acc[r][e] = fmaf(xv[r].z, g[e].z, acc[r][e]);
                acc[r][e] = fmaf(xv[r].w, g[e].w, acc[r][e]);
            }
    }

    // ---- Fold-reduction: 56 shuffles (was 192). After this, every lane
    // holds all 8 logits of row (lane&3), summed over all 64 lanes. ----
    const int rsel = lane & 1;
    float a2[2][8];
#pragma unroll
    for (int j = 0; j < 2; ++j)
#pragma unroll
        for (int e = 0; e < 8; ++e) {
            // keep row 2j+rsel; partner (lane^1) evaluates the "other"
            // expression as acc[2j+rsel], i.e. exactly the row we keep.
            const float mine  = rsel ? acc[2 * j + 1][e] : acc[2 * j][e];
            const float other = rsel ? acc[2 * j][e]     : acc[2 * j + 1][e];
            a2[j][e] = mine + __shfl_xor(other, 1);
        }
    const int sel = (lane >> 1) & 1;
    float a1[8];
#pragma unroll
    for (int e = 0; e < 8; ++e) {
        const float mine  = sel ? a2[1][e] : a2[0][e];
        const float other = sel ? a2[0][e] : a2[1][e];
        a1[e] = mine + __shfl_xor(other, 2);
    }
#pragma unroll
    for (int e = 0; e < 8; ++e) {
        float v = a1[e];
        v += __shfl_xor(v, 4);
        v += __shfl_xor(v, 8);
        v += __shfl_xor(v, 16);
        v += __shfl_xor(v, 32);
        a1[e] = v;   // logit of (row = lane&3, expert = e)
    }

    // ---- per-lane top-2 (lowest-index tie-break), values tracked inline ----
    int s0 = 0; float b0 = a1[0];
#pragma unroll
    for (int e = 1; e < 8; ++e)
        if (a1[e] > b0) { b0 = a1[e]; s0 = e; }
    int s1 = 0; float b1 = -3.4e38f;
#pragma unroll
    for (int e = 0; e < 8; ++e) {
        const bool t = (e != s0) && (a1[e] > b1);
        b1 = t ? a1[e] : b1;
        s1 = t ? e : s1;
    }
    const float d  = expf(b1 - b0);          // <= 1
    const float w0 = 1.0f / (1.0f + d);      // p0/(p0+p1)
    const float w1 = d * w0;                 // p1/(p0+p1)

    float* out_w = out;                            // [N, 2]
    float* out_m = out + 2 * kN;                   // [E, 2, N]
    float* out_l = out + 2 * kN + 2 * kE * kN;     // [N, 8]

    const int row = lane & 3;
    const int q   = lane >> 2;                     // 0..15

    // mask: lane = em*8 + km*4 + row  (bijective over 8x2x4 = 64 slots)
    {
        const int em = lane >> 3;
        const int km = (lane >> 2) & 1;
        const int ss = km ? s1 : s0;
        out_m[(long)em * (2 * kN) + (long)km * kN + (n0 + row)] =
            (ss == em) ? 1.0f : 0.0f;
    }
    // weights: lanes 0..7 -> (row = lane&3, k = lane>>2)
    if (lane < 8)
        out_w[(long)(n0 + row) * 2 + q] = q ? w1 : w0;
    // logits: lanes 0..31 -> (row = lane&3, e = lane>>2)
    if (lane < 32) {
        float v = a1[0];
#pragma unroll
        for (int e = 1; e < 8; ++e)
            v = (q == e) ? a1[e] : v;
        out_l[(long)(n0 + row) * 8 + q] = v;
    }
}

extern "C" void kernel_launch(void* const* d_in, const int* in_sizes, int n_in,
                              void* d_out, int out_size, void* d_ws, size_t ws_size,
                              hipStream_t stream)
{
    (void)in_sizes; (void)n_in; (void)d_ws; (void)ws_size; (void)out_size;
    const float* x  = (const float*)d_in[0];
    const float* gw = (const float*)d_in[1];
    float* out = (float*)d_out;

    dim3 grid(kN / 16);   // 1024 blocks, 16 rows each, 4 blocks/CU
    dim3 block(256);
    moe_router_kernel<<<grid, block, 0, stream>>>(x, gw, out);
}